// Round 2
// baseline (544.892 us; speedup 1.0000x reference)
//
#include <hip/hip_runtime.h>
#include <hip/hip_bf16.h>

#define NN 1024   // nodes = 32*32
#define EE 1984   // grid edges

// ---------------- edge index -> endpoints (matches grid_edges) ----------------
__device__ __forceinline__ void edge_uv(int e, int* u, int* v) {
    if (e < 992) {             // horizontal: idx[:, :-1] -> idx[:, 1:]
        int r = e / 31, c = e - r * 31;
        *u = r * 32 + c; *v = *u + 1;
    } else {                   // vertical: idx[:-1, :] -> idx[1:, :]
        *u = e - 992; *v = *u + 32;
    }
}

// ---------------- conv 1x1 : out[b,co,n] = sum_ci w[co,ci] * in[b,ci,n] ------
__global__ __launch_bounds__(128) void conv1x1_kernel(
    const float* __restrict__ in, const float* __restrict__ w,
    float* __restrict__ out, int Cin, int Cout) {
    int n   = blockIdx.x * 128 + threadIdx.x;
    int co0 = blockIdx.y * 8;
    int b   = blockIdx.z;
    const float* ip = in + (size_t)b * Cin * NN + n;
    float acc[8] = {0.f,0.f,0.f,0.f,0.f,0.f,0.f,0.f};
#pragma unroll 4
    for (int ci = 0; ci < Cin; ++ci) {
        float xv = ip[(size_t)ci * NN];
#pragma unroll
        for (int j = 0; j < 8; ++j)
            acc[j] += w[(size_t)(co0 + j) * Cin + ci] * xv;
    }
    size_t ob = ((size_t)b * Cout + co0) * NN + n;
#pragma unroll
    for (int j = 0; j < 8; ++j) out[ob + (size_t)j * NN] = acc[j];
}

// ---------------- conv 3x3 (pad 1), 64->64, + bn/relu or +res/relu ----------
// mode 0: out = relu(bn(conv(in)))     mode 1: out = relu(conv(in) + res)
__global__ __launch_bounds__(256) void conv3x3_kernel(
    const float* __restrict__ in, const float* __restrict__ w,
    const float* __restrict__ gg, const float* __restrict__ bb,
    const float* __restrict__ mm, const float* __restrict__ vv,
    const float* __restrict__ res, float* __restrict__ out, int mode) {
    int co = blockIdx.x, b = blockIdx.y, tid = threadIdx.x;
    __shared__ float pl[NN];
    const float* ip = in + (size_t)b * 64 * NN;
    float acc[4] = {0.f,0.f,0.f,0.f};
    for (int ci = 0; ci < 64; ++ci) {
        __syncthreads();
#pragma unroll
        for (int k = 0; k < 4; ++k)
            pl[tid + k * 256] = ip[(size_t)ci * NN + tid + k * 256];
        __syncthreads();
        float wv[9];
#pragma unroll
        for (int q = 0; q < 9; ++q) wv[q] = w[((size_t)co * 64 + ci) * 9 + q];
#pragma unroll
        for (int k = 0; k < 4; ++k) {
            int p = tid + k * 256;
            int r = p >> 5, c = p & 31;
            float s = 0.f;
#pragma unroll
            for (int dy = -1; dy <= 1; ++dy)
#pragma unroll
                for (int dx = -1; dx <= 1; ++dx) {
                    int rr = r + dy, cc = c + dx;
                    float xv = (rr >= 0 && rr < 32 && cc >= 0 && cc < 32)
                                   ? pl[rr * 32 + cc] : 0.f;
                    s += wv[(dy + 1) * 3 + (dx + 1)] * xv;
                }
            acc[k] += s;
        }
    }
    float scale = 1.f, bias = 0.f;
    if (mode == 0) {
        float sc = gg[co] * rsqrtf(vv[co] + 1e-5f);
        scale = sc; bias = bb[co] - mm[co] * sc;
    }
    size_t ob = ((size_t)b * 64 + co) * NN;
#pragma unroll
    for (int k = 0; k < 4; ++k) {
        int p = tid + k * 256;
        float val = (mode == 0) ? (acc[k] * scale + bias) : (acc[k] + res[ob + p]);
        out[ob + p] = fmaxf(val, 0.f);
    }
}

// ---------------- edge distances: dist[b,e] = ||fm[b,:,u]-fm[b,:,v]||^2 ------
__global__ __launch_bounds__(256) void dist_kernel(
    const float* __restrict__ fm, float* __restrict__ dist) {
    int e = blockIdx.x * 256 + threadIdx.x;
    int b = blockIdx.y;
    if (e >= EE) return;
    int u, v; edge_uv(e, &u, &v);
    const float* fp = fm + (size_t)b * 1024 * NN;
    float s = 0.f;
    for (int c = 0; c < 1024; ++c) {
        float d = fp[(size_t)c * NN + u] - fp[(size_t)c * NN + v];
        s += d * d;
    }
    dist[b * EE + e] = s;
}

// ------- reference-faithful Boruvka (re-singleton variant) + BFS + depth -----
// One block (1024 threads) per batch. Emulates the JAX reference exactly:
//  - 14 rounds; each round: per-label min cut edge (rank = (w,e) order),
//    non-root nodes reset to singletons, 2-cycle break, 12-step flatten.
//  - BFS from node 0 gives pn (-1 if unreachable).
//  - depth via 12-step pointer doubling with JAX -1 -> index N-1 wraparound.
__global__ __launch_bounds__(1024) void mst_kernel(
    const float* __restrict__ dist,
    int* __restrict__ pn_g, int* __restrict__ dep_g, int* __restrict__ maxd_g) {
    int b = blockIdx.x, tid = threadIdx.x;
    __shared__ int parent[NN], pnew[NN], pn[NN], dep[NN];
    __shared__ unsigned long long minkey[NN];
    __shared__ unsigned char mstm[EE];
    __shared__ int flag, maxd;
    const float* wb = dist + b * EE;

    parent[tid] = tid;
    for (int e = tid; e < EE; e += NN) mstm[e] = 0;
    if (tid == 0) maxd = 0;
    __syncthreads();

    // ---- 14 Boruvka body() iterations (reference: fori_loop(0, R+2)) ----
    for (int round = 0; round < 14; ++round) {
        minkey[tid] = ~0ULL;
        __syncthreads();
        for (int e = tid; e < EE; e += NN) {
            int u, v; edge_uv(e, &u, &v);
            int cu = parent[u], cv = parent[v];
            if (cu != cv) {
                unsigned long long key =
                    ((unsigned long long)__float_as_uint(wb[e]) << 32) | (unsigned)e;
                atomicMin(&minkey[cu], key);
                atomicMin(&minkey[cv], key);
            }
        }
        __syncthreads();
        // per-node: valid labels take min cut edge; everyone else re-singletons
        int np;
        if (minkey[tid] != ~0ULL) {
            int e = (int)(minkey[tid] & 0xffffffffULL);
            mstm[e] = 1;
            int u, v; edge_uv(e, &u, &v);
            int cu = parent[u], cv = parent[v];
            np = (cu == tid) ? cv : cu;      // other = where(cu[e]==nodes, cv[e], cu[e])
        } else {
            np = tid;                         // reference: pnew = nodes when !valid
        }
        pnew[tid] = np;
        __syncthreads();
        // break mutual (2-cycle) merges: smaller label becomes root
        int q = pnew[tid];
        int pq = pnew[q];
        __syncthreads();
        parent[tid] = (pq == tid && tid < q) ? tid : q;
        __syncthreads();
        // flatten: 12 iterations of q = q[q]
        for (int it = 0; it < 12; ++it) {
            int pp = parent[parent[tid]];
            __syncthreads();
            parent[tid] = pp;
            __syncthreads();
        }
    }

    // ---- BFS root at node 0 -> pn (-1 = unreachable) ----
    pn[tid] = (tid == 0) ? 0 : -1;
    __syncthreads();
    for (int iter = 0; iter < NN; ++iter) {
        if (tid == 0) flag = 0;
        __syncthreads();
        for (int e = tid; e < EE; e += NN) {
            if (mstm[e]) {
                int u, v; edge_uv(e, &u, &v);
                int pu = pn[u], pv = pn[v];
                if (pu >= 0 && pv < 0)      { pn[v] = u; flag = 1; }
                else if (pv >= 0 && pu < 0) { pn[u] = v; flag = 1; }
            }
        }
        __syncthreads();
        int f = flag;
        __syncthreads();
        if (!f) break;
    }

    // ---- depth via reference pointer doubling (12 iters, -1 wraps to N-1) ----
    dep[tid] = (tid != 0) ? 1 : 0;
    parent[tid] = pn[tid];
    __syncthreads();
    for (int it = 0; it < 12; ++it) {
        int pi = parent[tid];
        int j = (pi < 0) ? (NN + pi) : pi;   // JAX negative indexing
        int nd = dep[tid] + dep[j];
        int np2 = parent[j];
        __syncthreads();
        dep[tid] = nd;
        parent[tid] = np2;
        __syncthreads();
    }
    if (dep[tid] >= 1 && dep[tid] <= NN - 1) atomicMax(&maxd, dep[tid]);
    __syncthreads();
    pn_g[b * NN + tid]  = pn[tid];
    dep_g[b * NN + tid] = dep[tid];
    if (tid == 0) maxd_g[b] = maxd;
}

// ---------------- exact two-pass tree filter + normalize + fuse --------------
// block = (half, group, batch); handles 8 feat channels + its own ones channel.
// Scatter-based up sweep (LDS atomicAdd) so pn=-1 -> node N-1 (JAX .at[-1].add)
// is reproduced exactly; only levels 1..N-1 are processed (reference loops).
__global__ __launch_bounds__(1024) void treefilter_kernel(
    const float* __restrict__ feat,    // last_fm (B,64,N)
    const float* __restrict__ emb,     // (B,32,N)
    const float* __restrict__ latent,  // (B,64,N)
    const int* __restrict__ pn_g, const int* __restrict__ dep_g,
    const int* __restrict__ maxd_g, float* __restrict__ fusion) {
    int half = blockIdx.x, g = blockIdx.y, b = blockIdx.z;
    int v = threadIdx.x;
    __shared__ float agg[NN * 9];

    int p   = pn_g[b * NN + v];
    int j   = (p < 0) ? (NN + p) : p;    // JAX negative indexing
    int myd = dep_g[b * NN + v];
    int maxdep = maxd_g[b];
    bool act = (v != 0) && (myd >= 1) && (myd <= NN - 1);

    // per-node edge affinity to parent: exp(-||e_v - e_j||^2) over group's 8 ch
    const float* eb = emb + ((size_t)b * 32 + g * 8) * NN;
    float s = 0.f;
#pragma unroll
    for (int k = 0; k < 8; ++k) {
        float d = eb[(size_t)k * NN + v] - eb[(size_t)k * NN + j];
        s += d * d;
    }
    float wv = expf(-s);

    const float* fb = feat + ((size_t)b * 64 + g * 16 + half * 8) * NN;
#pragma unroll
    for (int c = 0; c < 8; ++c) agg[v * 9 + c] = fb[(size_t)c * NN + v];
    agg[v * 9 + 8] = 1.f;   // ones channel (normalizer)
    __syncthreads();

    // up sweep: levels maxdep..1 push w_v * agg_v into parent slot
    for (int lev = maxdep; lev >= 1; --lev) {
        if (act && myd == lev) {
#pragma unroll
            for (int c = 0; c < 9; ++c)
                atomicAdd(&agg[j * 9 + c], wv * agg[v * 9 + c]);
        }
        __syncthreads();
    }
    // down sweep: levels 1..maxdep, in place (parent slot already holds final F)
    for (int lev = 1; lev <= maxdep; ++lev) {
        if (act && myd == lev) {
#pragma unroll
            for (int c = 0; c < 9; ++c) {
                float a = agg[v * 9 + c];
                agg[v * 9 + c] = a + wv * (agg[j * 9 + c] - wv * a);
            }
        }
        __syncthreads();
    }
    // normalize by filtered ones-channel, add latent -> fusion
    float inv = 1.f / agg[v * 9 + 8];
    const float* lb = latent + ((size_t)b * 64 + g * 16 + half * 8) * NN;
    float* ob = fusion + ((size_t)b * 64 + g * 16 + half * 8) * NN;
#pragma unroll
    for (int c = 0; c < 8; ++c)
        ob[(size_t)c * NN + v] = lb[(size_t)c * NN + v] + agg[v * 9 + c] * inv;
}

// ----------------------------- host launcher ---------------------------------
extern "C" void kernel_launch(void* const* d_in, const int* in_sizes, int n_in,
                              void* d_out, int out_size, void* d_ws, size_t ws_size,
                              hipStream_t stream) {
    const float* fm      = (const float*)d_in[0];
    const float* last_fm = (const float*)d_in[1];
    const float* lat_w1  = (const float*)d_in[2];
    const float* lat_w3a = (const float*)d_in[3];
    const float* lat_g   = (const float*)d_in[4];
    const float* lat_b   = (const float*)d_in[5];
    const float* lat_m   = (const float*)d_in[6];
    const float* lat_v   = (const float*)d_in[7];
    const float* lat_w3b = (const float*)d_in[8];
    const float* ref_w1  = (const float*)d_in[9];
    const float* ref_w3a = (const float*)d_in[10];
    const float* ref_g   = (const float*)d_in[11];
    const float* ref_b   = (const float*)d_in[12];
    const float* ref_m   = (const float*)d_in[13];
    const float* ref_v   = (const float*)d_in[14];
    const float* ref_w3b = (const float*)d_in[15];
    const float* emb_w   = (const float*)d_in[16];
    float* out = (float*)d_out;

    // workspace layout (floats)
    float* ws      = (float*)d_ws;
    float* lat_x1  = ws;                  // 2*64*1024
    float* lat_t1  = lat_x1 + 131072;
    float* latent  = lat_t1 + 131072;
    float* dist    = latent + 131072;     // 2*1984 (pad to 4096)
    float* embed   = dist + 4096;         // 2*32*1024
    float* fusion  = embed + 65536;
    float* ref_x1  = fusion + 131072;
    float* ref_t1  = ref_x1 + 131072;
    int*   pn      = (int*)(ref_t1 + 131072);  // 2*1024
    int*   dep     = pn + 2048;
    int*   maxd    = dep + 2048;               // 2

    // ---- latent = refine_residual(fm, lat_*) ----
    conv1x1_kernel<<<dim3(8, 8, 2), 128, 0, stream>>>(fm, lat_w1, lat_x1, 1024, 64);
    conv3x3_kernel<<<dim3(64, 2), 256, 0, stream>>>(
        lat_x1, lat_w3a, lat_g, lat_b, lat_m, lat_v, nullptr, lat_t1, 0);
    conv3x3_kernel<<<dim3(64, 2), 256, 0, stream>>>(
        lat_t1, lat_w3b, nullptr, nullptr, nullptr, nullptr, lat_x1, latent, 1);

    // ---- MST on fm (reference-faithful) ----
    dist_kernel<<<dim3(8, 2), 256, 0, stream>>>(fm, dist);
    mst_kernel<<<dim3(2), 1024, 0, stream>>>(dist, pn, dep, maxd);

    // ---- embed + tree filter + fuse ----
    conv1x1_kernel<<<dim3(8, 4, 2), 128, 0, stream>>>(last_fm, emb_w, embed, 64, 32);
    treefilter_kernel<<<dim3(2, 4, 2), 1024, 0, stream>>>(
        last_fm, embed, latent, pn, dep, maxd, fusion);

    // ---- out = refine_residual(fusion, ref_*) ----
    conv1x1_kernel<<<dim3(8, 8, 2), 128, 0, stream>>>(fusion, ref_w1, ref_x1, 64, 64);
    conv3x3_kernel<<<dim3(64, 2), 256, 0, stream>>>(
        ref_x1, ref_w3a, ref_g, ref_b, ref_m, ref_v, nullptr, ref_t1, 0);
    conv3x3_kernel<<<dim3(64, 2), 256, 0, stream>>>(
        ref_t1, ref_w3b, nullptr, nullptr, nullptr, nullptr, ref_x1, out, 1);
}

// Round 3
// 457.357 us; speedup vs baseline: 1.1914x; 1.1914x over previous
//
#include <hip/hip_runtime.h>
#include <hip/hip_bf16.h>

#define NN 1024   // nodes = 32*32
#define EE 1984   // grid edges

// ---------------- edge index -> endpoints (matches grid_edges) ----------------
__device__ __forceinline__ void edge_uv(int e, int* u, int* v) {
    if (e < 992) {             // horizontal: idx[:, :-1] -> idx[:, 1:]
        int r = e / 31, c = e - r * 31;
        *u = r * 32 + c; *v = *u + 1;
    } else {                   // vertical: idx[:-1, :] -> idx[1:, :]
        *u = e - 992; *v = *u + 32;
    }
}

// ---------------- conv 1x1, split-K: block = 64 px x 4 kchunks, 8 couts ------
// grid (NN/64, Cout/8, B)
template <int CIN>
__global__ __launch_bounds__(256) void conv1x1_k(
    const float* __restrict__ in, const float* __restrict__ w,
    float* __restrict__ out, int Cout) {
    constexpr int CHUNK = CIN / 4;
    __shared__ float wsm[8 * CIN];
    __shared__ float red[256 * 8];
    int tid = threadIdx.x;
    int n0  = blockIdx.x * 64;
    int co0 = blockIdx.y * 8;
    int b   = blockIdx.z;
    // stage 8 weight rows (contiguous in w) into LDS
    for (int i = tid; i < 8 * CIN; i += 256)
        wsm[i] = w[(size_t)co0 * CIN + i];
    __syncthreads();
    int px = tid & 63, kc = tid >> 6;
    const float* ip = in + (size_t)b * CIN * NN + n0 + px;
    float acc[8] = {0.f,0.f,0.f,0.f,0.f,0.f,0.f,0.f};
    for (int ci = kc * CHUNK; ci < (kc + 1) * CHUNK; ++ci) {
        float xv = ip[(size_t)ci * NN];
#pragma unroll
        for (int j = 0; j < 8; ++j)
            acc[j] += wsm[j * CIN + ci] * xv;
    }
#pragma unroll
    for (int j = 0; j < 8; ++j) red[(kc * 64 + px) * 8 + j] = acc[j];
    __syncthreads();
    if (kc == 0) {
        size_t ob = ((size_t)b * Cout + co0) * NN + n0 + px;
#pragma unroll
        for (int j = 0; j < 8; ++j) {
            float s = red[px * 8 + j] + red[(64 + px) * 8 + j]
                    + red[(128 + px) * 8 + j] + red[(192 + px) * 8 + j];
            out[ob + (size_t)j * NN] = s;
        }
    }
}

// ---------------- conv 3x3 (pad 1), 64->64, bulk LDS staging -----------------
// block = 256 px (8 rows x 32); grid (4 row-tiles, 64 co, B)
// mode 0: out = relu(bn(conv(in)))     mode 1: out = relu(conv(in) + res)
__global__ __launch_bounds__(256) void conv3x3_kernel(
    const float* __restrict__ in, const float* __restrict__ w,
    const float* __restrict__ gg, const float* __restrict__ bb,
    const float* __restrict__ mm, const float* __restrict__ vv,
    const float* __restrict__ res, float* __restrict__ out, int mode) {
    __shared__ float pl[64 * 320];        // 64 planes x 10 halo rows x 32
    int tid = threadIdx.x;
    int r0  = blockIdx.x * 8;
    int co  = blockIdx.y, b = blockIdx.z;
    const float* ip = in + (size_t)b * 64 * NN;
    for (int idx = tid; idx < 64 * 320; idx += 256) {
        int ci = idx / 320, o = idx - ci * 320;
        int row = r0 - 1 + (o >> 5), col = o & 31;
        pl[idx] = (row >= 0 && row < 32) ? ip[(size_t)ci * NN + row * 32 + col] : 0.f;
    }
    __syncthreads();
    int r = tid >> 5, c = tid & 31;       // local row 0..7
    const float* wp = w + (size_t)co * 64 * 9;
    float acc = 0.f;
    for (int ci = 0; ci < 64; ++ci) {
        float wv[9];
#pragma unroll
        for (int q = 0; q < 9; ++q) wv[q] = wp[ci * 9 + q];   // uniform -> scalar
        float s = 0.f;
#pragma unroll
        for (int dy = 0; dy < 3; ++dy) {
            const float* row = &pl[ci * 320 + (r + dy) * 32];
#pragma unroll
            for (int dx = -1; dx <= 1; ++dx) {
                int cc = c + dx;
                float xv = (cc >= 0 && cc < 32) ? row[cc] : 0.f;
                s += wv[dy * 3 + (dx + 1)] * xv;
            }
        }
        acc += s;
    }
    float val;
    size_t op = ((size_t)b * 64 + co) * NN + r0 * 32 + tid;
    if (mode == 0) {
        float sc = gg[co] * rsqrtf(vv[co] + 1e-5f);
        val = acc * sc + (bb[co] - mm[co] * sc);
    } else {
        val = acc + res[op];
    }
    out[op] = fmaxf(val, 0.f);
}

// ---------------- edge distances, split-K: 64 edges x 4 kchunks --------------
__global__ __launch_bounds__(256) void dist_kernel(
    const float* __restrict__ fm, float* __restrict__ dist) {
    __shared__ float red[256];
    int tid = threadIdx.x, b = blockIdx.y;
    int le = tid & 63, kc = tid >> 6;
    int e = blockIdx.x * 64 + le;
    float s = 0.f;
    if (e < EE) {
        int u, v; edge_uv(e, &u, &v);
        const float* fp = fm + (size_t)b * 1024 * NN;
        for (int c = kc * 256; c < kc * 256 + 256; ++c) {
            float d = fp[(size_t)c * NN + u] - fp[(size_t)c * NN + v];
            s += d * d;
        }
    }
    red[tid] = s;
    __syncthreads();
    if (kc == 0 && e < EE)
        dist[b * EE + e] = red[le] + red[64 + le] + red[128 + le] + red[192 + le];
}

// ------- reference-faithful Boruvka (re-singleton variant) + BFS + depth -----
__global__ __launch_bounds__(1024) void mst_kernel(
    const float* __restrict__ dist,
    int* __restrict__ pn_g, int* __restrict__ dep_g, int* __restrict__ maxd_g) {
    int b = blockIdx.x, tid = threadIdx.x;
    __shared__ int parent[NN], pnew[NN], pn[NN], dep[NN];
    __shared__ unsigned long long minkey[NN];
    __shared__ unsigned char mstm[EE];
    __shared__ int flag, maxd;
    const float* wb = dist + b * EE;

    parent[tid] = tid;
    for (int e = tid; e < EE; e += NN) mstm[e] = 0;
    if (tid == 0) maxd = 0;
    __syncthreads();

    for (int round = 0; round < 14; ++round) {
        minkey[tid] = ~0ULL;
        __syncthreads();
        for (int e = tid; e < EE; e += NN) {
            int u, v; edge_uv(e, &u, &v);
            int cu = parent[u], cv = parent[v];
            if (cu != cv) {
                unsigned long long key =
                    ((unsigned long long)__float_as_uint(wb[e]) << 32) | (unsigned)e;
                atomicMin(&minkey[cu], key);
                atomicMin(&minkey[cv], key);
            }
        }
        __syncthreads();
        int np;
        if (minkey[tid] != ~0ULL) {
            int e = (int)(minkey[tid] & 0xffffffffULL);
            mstm[e] = 1;
            int u, v; edge_uv(e, &u, &v);
            int cu = parent[u], cv = parent[v];
            np = (cu == tid) ? cv : cu;
        } else {
            np = tid;                         // reference: re-singleton when !valid
        }
        pnew[tid] = np;
        __syncthreads();
        int q = pnew[tid];
        int pq = pnew[q];
        __syncthreads();
        parent[tid] = (pq == tid && tid < q) ? tid : q;
        __syncthreads();
        for (int it = 0; it < 12; ++it) {
            int pp = parent[parent[tid]];
            __syncthreads();
            parent[tid] = pp;
            __syncthreads();
        }
    }

    // BFS root at node 0 -> pn (-1 = unreachable)
    pn[tid] = (tid == 0) ? 0 : -1;
    __syncthreads();
    for (int iter = 0; iter < NN; ++iter) {
        if (tid == 0) flag = 0;
        __syncthreads();
        for (int e = tid; e < EE; e += NN) {
            if (mstm[e]) {
                int u, v; edge_uv(e, &u, &v);
                int pu = pn[u], pv = pn[v];
                if (pu >= 0 && pv < 0)      { pn[v] = u; flag = 1; }
                else if (pv >= 0 && pu < 0) { pn[u] = v; flag = 1; }
            }
        }
        __syncthreads();
        int f = flag;
        __syncthreads();
        if (!f) break;
    }

    // depth via reference pointer doubling (12 iters, -1 wraps to N-1)
    dep[tid] = (tid != 0) ? 1 : 0;
    parent[tid] = pn[tid];
    __syncthreads();
    for (int it = 0; it < 12; ++it) {
        int pi = parent[tid];
        int j = (pi < 0) ? (NN + pi) : pi;
        int nd = dep[tid] + dep[j];
        int np2 = parent[j];
        __syncthreads();
        dep[tid] = nd;
        parent[tid] = np2;
        __syncthreads();
    }
    if (dep[tid] >= 1 && dep[tid] <= NN - 1) atomicMax(&maxd, dep[tid]);
    __syncthreads();
    pn_g[b * NN + tid]  = pn[tid];
    dep_g[b * NN + tid] = dep[tid];
    if (tid == 0) maxd_g[b] = maxd;
}

// ---------------- exact two-pass tree filter + normalize + fuse --------------
__global__ __launch_bounds__(1024) void treefilter_kernel(
    const float* __restrict__ feat,    // last_fm (B,64,N)
    const float* __restrict__ emb,     // (B,32,N)
    const float* __restrict__ latent,  // (B,64,N)
    const int* __restrict__ pn_g, const int* __restrict__ dep_g,
    const int* __restrict__ maxd_g, float* __restrict__ fusion) {
    int half = blockIdx.x, g = blockIdx.y, b = blockIdx.z;
    int v = threadIdx.x;
    __shared__ float agg[NN * 9];

    int p   = pn_g[b * NN + v];
    int j   = (p < 0) ? (NN + p) : p;    // JAX negative indexing
    int myd = dep_g[b * NN + v];
    int maxdep = maxd_g[b];
    bool act = (v != 0) && (myd >= 1) && (myd <= NN - 1);

    const float* eb = emb + ((size_t)b * 32 + g * 8) * NN;
    float s = 0.f;
#pragma unroll
    for (int k = 0; k < 8; ++k) {
        float d = eb[(size_t)k * NN + v] - eb[(size_t)k * NN + j];
        s += d * d;
    }
    float wv = expf(-s);

    const float* fb = feat + ((size_t)b * 64 + g * 16 + half * 8) * NN;
#pragma unroll
    for (int c = 0; c < 8; ++c) agg[v * 9 + c] = fb[(size_t)c * NN + v];
    agg[v * 9 + 8] = 1.f;
    __syncthreads();

    for (int lev = maxdep; lev >= 1; --lev) {
        if (act && myd == lev) {
#pragma unroll
            for (int c = 0; c < 9; ++c)
                atomicAdd(&agg[j * 9 + c], wv * agg[v * 9 + c]);
        }
        __syncthreads();
    }
    for (int lev = 1; lev <= maxdep; ++lev) {
        if (act && myd == lev) {
#pragma unroll
            for (int c = 0; c < 9; ++c) {
                float a = agg[v * 9 + c];
                agg[v * 9 + c] = a + wv * (agg[j * 9 + c] - wv * a);
            }
        }
        __syncthreads();
    }
    float inv = 1.f / agg[v * 9 + 8];
    const float* lb = latent + ((size_t)b * 64 + g * 16 + half * 8) * NN;
    float* ob = fusion + ((size_t)b * 64 + g * 16 + half * 8) * NN;
#pragma unroll
    for (int c = 0; c < 8; ++c)
        ob[(size_t)c * NN + v] = lb[(size_t)c * NN + v] + agg[v * 9 + c] * inv;
}

// ----------------------------- host launcher ---------------------------------
extern "C" void kernel_launch(void* const* d_in, const int* in_sizes, int n_in,
                              void* d_out, int out_size, void* d_ws, size_t ws_size,
                              hipStream_t stream) {
    const float* fm      = (const float*)d_in[0];
    const float* last_fm = (const float*)d_in[1];
    const float* lat_w1  = (const float*)d_in[2];
    const float* lat_w3a = (const float*)d_in[3];
    const float* lat_g   = (const float*)d_in[4];
    const float* lat_b   = (const float*)d_in[5];
    const float* lat_m   = (const float*)d_in[6];
    const float* lat_v   = (const float*)d_in[7];
    const float* lat_w3b = (const float*)d_in[8];
    const float* ref_w1  = (const float*)d_in[9];
    const float* ref_w3a = (const float*)d_in[10];
    const float* ref_g   = (const float*)d_in[11];
    const float* ref_b   = (const float*)d_in[12];
    const float* ref_m   = (const float*)d_in[13];
    const float* ref_v   = (const float*)d_in[14];
    const float* ref_w3b = (const float*)d_in[15];
    const float* emb_w   = (const float*)d_in[16];
    float* out = (float*)d_out;

    float* ws      = (float*)d_ws;
    float* lat_x1  = ws;                  // 2*64*1024
    float* lat_t1  = lat_x1 + 131072;
    float* latent  = lat_t1 + 131072;
    float* dist    = latent + 131072;     // 2*1984 (pad to 4096)
    float* embed   = dist + 4096;         // 2*32*1024
    float* fusion  = embed + 65536;
    float* ref_x1  = fusion + 131072;
    float* ref_t1  = ref_x1 + 131072;
    int*   pn      = (int*)(ref_t1 + 131072);
    int*   dep     = pn + 2048;
    int*   maxd    = dep + 2048;

    // ---- latent = refine_residual(fm, lat_*) ----
    conv1x1_k<1024><<<dim3(16, 8, 2), 256, 0, stream>>>(fm, lat_w1, lat_x1, 64);
    conv3x3_kernel<<<dim3(4, 64, 2), 256, 0, stream>>>(
        lat_x1, lat_w3a, lat_g, lat_b, lat_m, lat_v, nullptr, lat_t1, 0);
    conv3x3_kernel<<<dim3(4, 64, 2), 256, 0, stream>>>(
        lat_t1, lat_w3b, nullptr, nullptr, nullptr, nullptr, lat_x1, latent, 1);

    // ---- MST on fm (reference-faithful) ----
    dist_kernel<<<dim3(31, 2), 256, 0, stream>>>(fm, dist);
    mst_kernel<<<dim3(2), 1024, 0, stream>>>(dist, pn, dep, maxd);

    // ---- embed + tree filter + fuse ----
    conv1x1_k<64><<<dim3(16, 4, 2), 256, 0, stream>>>(last_fm, emb_w, embed, 32);
    treefilter_kernel<<<dim3(2, 4, 2), 1024, 0, stream>>>(
        last_fm, embed, latent, pn, dep, maxd, fusion);

    // ---- out = refine_residual(fusion, ref_*) ----
    conv1x1_k<64><<<dim3(16, 8, 2), 256, 0, stream>>>(fusion, ref_w1, ref_x1, 64);
    conv3x3_kernel<<<dim3(4, 64, 2), 256, 0, stream>>>(
        ref_x1, ref_w3a, ref_g, ref_b, ref_m, ref_v, nullptr, ref_t1, 0);
    conv3x3_kernel<<<dim3(4, 64, 2), 256, 0, stream>>>(
        ref_t1, ref_w3b, nullptr, nullptr, nullptr, nullptr, ref_x1, out, 1);
}

// Round 4
// 336.483 us; speedup vs baseline: 1.6194x; 1.3592x over previous
//
#include <hip/hip_runtime.h>
#include <hip/hip_bf16.h>

#define NN 1024   // nodes = 32*32
#define EE 1984   // grid edges

// ---------------- edge index -> endpoints (matches grid_edges) ----------------
__device__ __forceinline__ void edge_uv(int e, int* u, int* v) {
    if (e < 992) {             // horizontal: idx[:, :-1] -> idx[:, 1:]
        int r = e / 31, c = e - r * 31;
        *u = r * 32 + c; *v = *u + 1;
    } else {                   // vertical: idx[:-1, :] -> idx[1:, :]
        *u = e - 992; *v = *u + 32;
    }
}

// ======================= conv 1x1 tile (1024 threads) ========================
// 16 kchunks x 64 px, 8 couts. Weights via wave-uniform scalar loads.
// red: 8192 floats of LDS.
__device__ void conv1x1_tile(const float* __restrict__ in, const float* __restrict__ w,
                             float* __restrict__ out, int CIN, int Cout,
                             int b, int co0, int n0, float* red) {
    int tid = threadIdx.x;
    int px = tid & 63, kc = tid >> 6;
    int kcu = __builtin_amdgcn_readfirstlane(kc);   // provably wave-uniform -> s_loads
    int KCH = CIN >> 4;
    const float* ip = in + (size_t)b * CIN * NN + n0 + px;
    const float* wr = w + (size_t)co0 * CIN;
    float acc[8] = {0.f,0.f,0.f,0.f,0.f,0.f,0.f,0.f};
    for (int ci = kcu * KCH; ci < kcu * KCH + KCH; ++ci) {
        float xv = ip[(size_t)ci * NN];
#pragma unroll
        for (int j = 0; j < 8; ++j)
            acc[j] += wr[j * CIN + ci] * xv;
    }
#pragma unroll
    for (int j = 0; j < 8; ++j) red[j * 1024 + tid] = acc[j];
    __syncthreads();
    for (int s = 8; s >= 1; s >>= 1) {
        if (kc < s) {
#pragma unroll
            for (int j = 0; j < 8; ++j)
                red[j * 1024 + kc * 64 + px] += red[j * 1024 + (kc + s) * 64 + px];
        }
        __syncthreads();
    }
    if (kc == 0) {
        size_t ob = ((size_t)b * Cout + co0) * NN + n0 + px;
#pragma unroll
        for (int j = 0; j < 8; ++j) out[ob + (size_t)j * NN] = red[j * 1024 + px];
    }
}

// ======================= edge-dist tile (1024 threads) =======================
// 64 edges x 16 kchunks of 64 channels. red: 1024 floats of LDS.
__device__ void dist_tile(const float* __restrict__ fm, float* __restrict__ dist,
                          int b, int eb, float* red) {
    int tid = threadIdx.x;
    int le = tid & 63, kc = tid >> 6;
    int kcu = __builtin_amdgcn_readfirstlane(kc);
    int e = eb * 64 + le;                  // 31*64 == 1984 exact, no guard
    int u, v; edge_uv(e, &u, &v);
    const float* fp = fm + (size_t)b * 1024 * NN;
    float s = 0.f;
    for (int c = kcu * 64; c < kcu * 64 + 64; ++c) {
        float d = fp[(size_t)c * NN + u] - fp[(size_t)c * NN + v];
        s += d * d;
    }
    red[tid] = s;
    __syncthreads();
    for (int ss = 8; ss >= 1; ss >>= 1) {
        if (kc < ss) red[kc * 64 + le] += red[(kc + ss) * 64 + le];
        __syncthreads();
    }
    if (kc == 0) dist[b * EE + e] = red[le];
}

// ================== conv 3x3 body (256 threads, 2-half staging) ==============
// mode 0: out = relu(bn(conv(in)))     mode 1: out = relu(conv(in) + res)
__device__ void conv3x3_body(const float* __restrict__ in, const float* __restrict__ w,
                             const float* __restrict__ gg, const float* __restrict__ bb,
                             const float* __restrict__ mm, const float* __restrict__ vv,
                             const float* __restrict__ res, float* __restrict__ out,
                             int mode, int b, int co, int r0, float* pl) {
    int tid = threadIdx.x;
    const float* ip = in + (size_t)b * 64 * NN;
    const float* wp = w + (size_t)co * 64 * 9;
    int r = tid >> 5, c = tid & 31;
    float acc = 0.f;
    for (int h = 0; h < 2; ++h) {
        __syncthreads();
        for (int idx = tid; idx < 32 * 320; idx += 256) {
            int ci = idx / 320, o = idx - ci * 320;
            int row = r0 - 1 + (o >> 5), col = o & 31;
            pl[idx] = (row >= 0 && row < 32)
                          ? ip[(size_t)(h * 32 + ci) * NN + row * 32 + col] : 0.f;
        }
        __syncthreads();
        for (int ci = 0; ci < 32; ++ci) {
            float wv[9];
#pragma unroll
            for (int q = 0; q < 9; ++q) wv[q] = wp[(h * 32 + ci) * 9 + q];  // uniform
            float s = 0.f;
#pragma unroll
            for (int dy = 0; dy < 3; ++dy) {
                const float* row = &pl[ci * 320 + (r + dy) * 32];
#pragma unroll
                for (int dx = -1; dx <= 1; ++dx) {
                    int cc = c + dx;
                    float xv = (cc >= 0 && cc < 32) ? row[cc] : 0.f;
                    s += wv[dy * 3 + (dx + 1)] * xv;
                }
            }
            acc += s;
        }
    }
    float val;
    size_t op = ((size_t)b * 64 + co) * NN + r0 * 32 + tid;
    if (mode == 0) {
        float sc = gg[co] * rsqrtf(vv[co] + 1e-5f);
        val = acc * sc + (bb[co] - mm[co] * sc);
    } else {
        val = acc + res[op];
    }
    out[op] = fmaxf(val, 0.f);
}

// ===================== MST body (256 threads, 4 nodes/thread) ================
// Reference-faithful: 14 rounds of re-singleton Boruvka, 10-step flatten
// (== reference's 12: 2^10 covers any chain), BFS root, 12-step depth doubling
// with JAX -1 -> N-1 wraparound.
__device__ void mst_body(const float* __restrict__ dist,
                         int* __restrict__ pn_g, int* __restrict__ dep_g,
                         int* __restrict__ maxd_g, int b,
                         int* parent, int* pnw, int* pn, int* dep, int* scratch,
                         unsigned long long* minkey, unsigned char* mstm,
                         float* distc, int* flag) {
    int tid = threadIdx.x;
    const float* wb = dist + b * EE;
#pragma unroll
    for (int k = 0; k < 4; ++k) parent[tid + k * 256] = tid + k * 256;
    for (int e = tid; e < EE; e += 256) { distc[e] = wb[e]; mstm[e] = 0; }
    __syncthreads();

    for (int round = 0; round < 14; ++round) {
#pragma unroll
        for (int k = 0; k < 4; ++k) minkey[tid + k * 256] = ~0ULL;
        __syncthreads();
        for (int e = tid; e < EE; e += 256) {
            int u, v; edge_uv(e, &u, &v);
            int cu = parent[u], cv = parent[v];
            if (cu != cv) {
                unsigned long long key =
                    ((unsigned long long)__float_as_uint(distc[e]) << 32) | (unsigned)e;
                atomicMin(&minkey[cu], key);
                atomicMin(&minkey[cv], key);
            }
        }
        __syncthreads();
#pragma unroll
        for (int k = 0; k < 4; ++k) {
            int v = tid + k * 256; int np;
            if (minkey[v] != ~0ULL) {
                int e = (int)(minkey[v] & 0xffffffffULL);
                mstm[e] = 1;
                int eu, ev; edge_uv(e, &eu, &ev);
                int cu = parent[eu], cv = parent[ev];
                np = (cu == v) ? cv : cu;
            } else np = v;                 // reference: re-singleton when !valid
            pnw[v] = np;
        }
        __syncthreads();
#pragma unroll
        for (int k = 0; k < 4; ++k) {      // break mutual 2-cycles
            int v = tid + k * 256;
            int q = pnw[v];
            int pq = pnw[q];
            parent[v] = (pq == v && v < q) ? v : q;
        }
        __syncthreads();
        int* src = parent; int* dst = scratch;
        for (int it = 0; it < 10; ++it) {  // flatten; ends in `parent` (10 even)
#pragma unroll
            for (int k = 0; k < 4; ++k) {
                int v = tid + k * 256;
                dst[v] = src[src[v]];
            }
            __syncthreads();
            int* t = src; src = dst; dst = t;
        }
    }

    // BFS root at node 0 -> pn (-1 = unreachable)
#pragma unroll
    for (int k = 0; k < 4; ++k) { int v = tid + k * 256; pn[v] = (v == 0) ? 0 : -1; }
    __syncthreads();
    for (int iter = 0; iter < NN; ++iter) {
        if (tid == 0) *flag = 0;
        __syncthreads();
        for (int e = tid; e < EE; e += 256) {
            if (mstm[e]) {
                int u, v; edge_uv(e, &u, &v);
                int pu = pn[u], pv = pn[v];
                if (pu >= 0 && pv < 0)      { pn[v] = u; *flag = 1; }
                else if (pv >= 0 && pu < 0) { pn[u] = v; *flag = 1; }
            }
        }
        __syncthreads();
        int f = *flag;
        __syncthreads();
        if (!f) break;
    }

    // depth: 12-step pointer doubling, -1 wraps to N-1 (JAX semantics)
#pragma unroll
    for (int k = 0; k < 4; ++k) {
        int v = tid + k * 256;
        dep[v] = (v != 0) ? 1 : 0;
        parent[v] = pn[v];
    }
    __syncthreads();
    int* dA = dep; int* dB = scratch; int* pA = parent; int* pB = pnw;
    for (int it = 0; it < 12; ++it) {
#pragma unroll
        for (int k = 0; k < 4; ++k) {
            int v = tid + k * 256;
            int p = pA[v];
            int j = (p < 0) ? (NN + p) : p;
            dB[v] = dA[v] + dA[j];
            pB[v] = pA[j];
        }
        __syncthreads();
        int* t = dA; dA = dB; dB = t;
        t = pA; pA = pB; pB = t;
    }                                       // 12 even -> result in dep/parent
    if (tid == 0) *flag = 0;
    __syncthreads();
    int lm = 0;
#pragma unroll
    for (int k = 0; k < 4; ++k) {
        int d = dA[tid + k * 256];
        if (d >= 1 && d <= NN - 1 && d > lm) lm = d;
    }
    atomicMax(flag, lm);
    __syncthreads();
#pragma unroll
    for (int k = 0; k < 4; ++k) {
        int v = tid + k * 256;
        pn_g[b * NN + v]  = pn[v];
        dep_g[b * NN + v] = dA[v];
    }
    if (tid == 0) maxd_g[b] = *flag;
}

// ========================= fused kernel 1 (1024 thr) =========================
// blocks [0,256): big conv1x1 (fm -> lat_x1); [256,318): dist; [318,446): embed
__global__ __launch_bounds__(1024) void k1_fused(
    const float* __restrict__ fm, const float* __restrict__ last_fm,
    const float* __restrict__ lat_w1, const float* __restrict__ emb_w,
    float* __restrict__ lat_x1, float* __restrict__ embed, float* __restrict__ dist) {
    __shared__ float smem[8192];
    int bx = blockIdx.x;
    if (bx < 256) {
        int b = bx >> 7, r = bx & 127;
        conv1x1_tile(fm, lat_w1, lat_x1, 1024, 64, b, (r >> 4) * 8, (r & 15) * 64, smem);
    } else if (bx < 318) {
        int i = bx - 256;
        dist_tile(fm, dist, i / 31, i % 31, smem);
    } else {
        int i = bx - 318;
        int b = i >> 6, r = i & 63;
        conv1x1_tile(last_fm, emb_w, embed, 64, 32, b, (r >> 4) * 8, (r & 15) * 64, smem);
    }
}

// ========================= fused kernel 2 (256 thr) ==========================
// blocks [0,512): conv3x3a (lat path); [512,514): MST
__global__ __launch_bounds__(256) void k2_fused(
    const float* __restrict__ lat_x1, const float* __restrict__ lat_w3a,
    const float* __restrict__ lat_g, const float* __restrict__ lat_b,
    const float* __restrict__ lat_m, const float* __restrict__ lat_v,
    float* __restrict__ lat_t1,
    const float* __restrict__ dist, int* __restrict__ pn_g,
    int* __restrict__ dep_g, int* __restrict__ maxd_g) {
    __shared__ float pl[32 * 320];
    __shared__ int parent[NN], pnw[NN], pn[NN], dep[NN], scratch[NN];
    __shared__ unsigned long long minkey[NN];
    __shared__ unsigned char mstm[EE];
    __shared__ float distc[EE];
    __shared__ int flag;
    int bx = blockIdx.x;
    if (bx < 512) {
        int b = bx >> 8, co = (bx >> 2) & 63, r0 = (bx & 3) * 8;
        conv3x3_body(lat_x1, lat_w3a, lat_g, lat_b, lat_m, lat_v,
                     nullptr, lat_t1, 0, b, co, r0, pl);
    } else {
        mst_body(dist, pn_g, dep_g, maxd_g, bx - 512,
                 parent, pnw, pn, dep, scratch, minkey, mstm, distc, &flag);
    }
}

// ===================== standalone conv kernels ===============================
__global__ __launch_bounds__(256) void conv3x3_kernel(
    const float* __restrict__ in, const float* __restrict__ w,
    const float* __restrict__ gg, const float* __restrict__ bb,
    const float* __restrict__ mm, const float* __restrict__ vv,
    const float* __restrict__ res, float* __restrict__ out, int mode) {
    __shared__ float pl[32 * 320];
    conv3x3_body(in, w, gg, bb, mm, vv, res, out, mode,
                 blockIdx.z, blockIdx.y, blockIdx.x * 8, pl);
}

__global__ __launch_bounds__(1024) void conv1x1_kernel(
    const float* __restrict__ in, const float* __restrict__ w,
    float* __restrict__ out, int CIN, int Cout) {
    __shared__ float red[8192];
    conv1x1_tile(in, w, out, CIN, Cout, blockIdx.z, blockIdx.y * 8,
                 blockIdx.x * 64, red);
}

// ============ tree filter (256 thr, 4 nodes/thread, 2 feat ch/blk) ===========
__global__ __launch_bounds__(256) void treefilter_kernel(
    const float* __restrict__ feat, const float* __restrict__ emb,
    const float* __restrict__ latent,
    const int* __restrict__ pn_g, const int* __restrict__ dep_g,
    const int* __restrict__ maxd_g, float* __restrict__ fusion) {
    int sub = blockIdx.x, g = blockIdx.y, b = blockIdx.z;
    int tid = threadIdx.x;
    __shared__ float agg[NN * 3];

    int jj[4], dd[4]; float ww[4];
    const float* eb = emb + ((size_t)b * 32 + g * 8) * NN;
    int c0 = g * 16 + sub * 2;
    const float* fb = feat + ((size_t)b * 64 + c0) * NN;
#pragma unroll
    for (int k = 0; k < 4; ++k) {
        int v = tid + k * 256;
        int p = pn_g[b * NN + v];
        int j = (p < 0) ? (NN + p) : p;     // JAX negative indexing
        jj[k] = j; dd[k] = dep_g[b * NN + v];
        float s = 0.f;
#pragma unroll
        for (int q = 0; q < 8; ++q) {
            float d = eb[(size_t)q * NN + v] - eb[(size_t)q * NN + j];
            s += d * d;
        }
        ww[k] = expf(-s);
        agg[v * 3 + 0] = fb[v];
        agg[v * 3 + 1] = fb[NN + v];
        agg[v * 3 + 2] = 1.f;
    }
    __syncthreads();
    int maxdep = maxd_g[b];
    for (int lev = maxdep; lev >= 1; --lev) {          // up sweep
#pragma unroll
        for (int k = 0; k < 4; ++k) {
            int v = tid + k * 256;
            if (v != 0 && dd[k] == lev) {
                int j = jj[k]; float w = ww[k];
                atomicAdd(&agg[j * 3 + 0], w * agg[v * 3 + 0]);
                atomicAdd(&agg[j * 3 + 1], w * agg[v * 3 + 1]);
                atomicAdd(&agg[j * 3 + 2], w * agg[v * 3 + 2]);
            }
        }
        __syncthreads();
    }
    for (int lev = 1; lev <= maxdep; ++lev) {          // down sweep (in place)
#pragma unroll
        for (int k = 0; k < 4; ++k) {
            int v = tid + k * 256;
            if (v != 0 && dd[k] == lev) {
                int j = jj[k]; float w = ww[k];
#pragma unroll
                for (int c = 0; c < 3; ++c) {
                    float a = agg[v * 3 + c];
                    agg[v * 3 + c] = a + w * (agg[j * 3 + c] - w * a);
                }
            }
        }
        __syncthreads();
    }
    const float* lb = latent + ((size_t)b * 64 + c0) * NN;
    float* ob = fusion + ((size_t)b * 64 + c0) * NN;
#pragma unroll
    for (int k = 0; k < 4; ++k) {
        int v = tid + k * 256;
        float inv = 1.f / agg[v * 3 + 2];
        ob[v]      = lb[v]      + agg[v * 3 + 0] * inv;
        ob[NN + v] = lb[NN + v] + agg[v * 3 + 1] * inv;
    }
}

// ----------------------------- host launcher ---------------------------------
extern "C" void kernel_launch(void* const* d_in, const int* in_sizes, int n_in,
                              void* d_out, int out_size, void* d_ws, size_t ws_size,
                              hipStream_t stream) {
    const float* fm      = (const float*)d_in[0];
    const float* last_fm = (const float*)d_in[1];
    const float* lat_w1  = (const float*)d_in[2];
    const float* lat_w3a = (const float*)d_in[3];
    const float* lat_g   = (const float*)d_in[4];
    const float* lat_b   = (const float*)d_in[5];
    const float* lat_m   = (const float*)d_in[6];
    const float* lat_v   = (const float*)d_in[7];
    const float* lat_w3b = (const float*)d_in[8];
    const float* ref_w1  = (const float*)d_in[9];
    const float* ref_w3a = (const float*)d_in[10];
    const float* ref_g   = (const float*)d_in[11];
    const float* ref_b   = (const float*)d_in[12];
    const float* ref_m   = (const float*)d_in[13];
    const float* ref_v   = (const float*)d_in[14];
    const float* ref_w3b = (const float*)d_in[15];
    const float* emb_w   = (const float*)d_in[16];
    float* out = (float*)d_out;

    float* ws      = (float*)d_ws;
    float* lat_x1  = ws;                  // 2*64*1024
    float* lat_t1  = lat_x1 + 131072;
    float* latent  = lat_t1 + 131072;
    float* dist    = latent + 131072;     // 2*1984 (pad to 4096)
    float* embed   = dist + 4096;         // 2*32*1024
    float* fusion  = embed + 65536;
    float* ref_x1  = fusion + 131072;
    float* ref_t1  = ref_x1 + 131072;
    int*   pn      = (int*)(ref_t1 + 131072);
    int*   dep     = pn + 2048;
    int*   maxd    = dep + 2048;

    // K1: big conv1x1 + edge distances + embed conv (all independent)
    k1_fused<<<446, 1024, 0, stream>>>(fm, last_fm, lat_w1, emb_w,
                                       lat_x1, embed, dist);
    // K2: conv3x3a (latent path) + MST (rides along on 2 blocks)
    k2_fused<<<514, 256, 0, stream>>>(lat_x1, lat_w3a, lat_g, lat_b, lat_m, lat_v,
                                      lat_t1, dist, pn, dep, maxd);
    // K3: conv3x3b -> latent
    conv3x3_kernel<<<dim3(4, 64, 2), 256, 0, stream>>>(
        lat_t1, lat_w3b, nullptr, nullptr, nullptr, nullptr, lat_x1, latent, 1);
    // K4: tree filter + normalize + fuse (+latent)
    treefilter_kernel<<<dim3(8, 4, 2), 256, 0, stream>>>(
        last_fm, embed, latent, pn, dep, maxd, fusion);
    // K5..K7: refine_residual(fusion, ref_*)
    conv1x1_kernel<<<dim3(16, 8, 2), 1024, 0, stream>>>(fusion, ref_w1, ref_x1, 64, 64);
    conv3x3_kernel<<<dim3(4, 64, 2), 256, 0, stream>>>(
        ref_x1, ref_w3a, ref_g, ref_b, ref_m, ref_v, nullptr, ref_t1, 0);
    conv3x3_kernel<<<dim3(4, 64, 2), 256, 0, stream>>>(
        ref_t1, ref_w3b, nullptr, nullptr, nullptr, nullptr, ref_x1, out, 1);
}